// Round 1
// baseline (89.448 us; speedup 1.0000x reference)
//
#include <hip/hip_runtime.h>
#include <hip/hip_bf16.h>

// Problem constants: B=16, Ci=16, Co=16, H=W=24, hidden=64.
// K table: K[dy47][dxi][o][i], dy47 = dy+23 in [0,47), dxi = dx+24 in [0,49)
// (dx padded one column of zeros on each side so dx-pairs never go OOB).
// v_pad: bf16 [b][y'=26][x'=40][i=16], y' = h+dy+1, x' = w+dx+d+8, zero-padded.

typedef __attribute__((ext_vector_type(8))) short bf16x8;
typedef __attribute__((ext_vector_type(4))) float f32x4;

#define KT_ELEMS (47*49*256)          // 589,568 bf16
#define VPAD_ELEMS (16*26*40*16)      // 266,240 bf16

// ---------------- Kernel 1: build K table ----------------
// grid 47 (one block per dy row), 256 threads. w2 staged transposed in LDS.
__global__ void build_ktable(const float* __restrict__ w1, const float* __restrict__ b1,
                             const float* __restrict__ w2, const float* __restrict__ b2,
                             __hip_bfloat16* __restrict__ kt)
{
    __shared__ float w2T[64*257];   // [j][oi], stride 257 to avoid bank conflicts
    __shared__ float hid[64];
    const int tid = threadIdx.x;
    const int dy47 = blockIdx.x;    // 0..46

    for (int q = 0; q < 64; ++q) {
        int idx = q*256 + tid;                       // coalesced read of w2 (256x64)
        w2T[(idx & 63)*257 + (idx >> 6)] = w2[idx];  // w2T[j][oi] = w2[oi][j]
    }
    const float ty = tanhf((float)(dy47 - 23) * (1.0f/6.0f));

    for (int dxi = 0; dxi < 49; ++dxi) {
        __syncthreads();   // protects hid from previous iteration
        if (dxi == 0 || dxi == 48) {
            kt[(dy47*49 + dxi)*256 + tid] = __float2bfloat16(0.0f);  // OOB pad column
            continue;
        }
        const float tx = tanhf((float)(dxi - 24) * (1.0f/6.0f));
        if (tid < 64) {
            float x = ty*w1[tid*2] + tx*w1[tid*2+1] + b1[tid];
            hid[tid] = 0.5f*x*(1.0f + erff(x*0.70710678118f));   // exact gelu
        }
        __syncthreads();
        float acc = b2[tid];
        #pragma unroll 8
        for (int j = 0; j < 64; ++j) acc += hid[j]*w2T[j*257 + tid];
        kt[(dy47*49 + dxi)*256 + tid] = __float2bfloat16(acc);
    }
}

// ---------------- Kernel 2: pad + transpose v to bf16 ----------------
__global__ void pad_v(const float* __restrict__ v, __hip_bfloat16* __restrict__ vpad)
{
    int idx = blockIdx.x*256 + threadIdx.x;      // [b][y][x][i]
    if (idx >= VPAD_ELEMS) return;
    int i = idx & 15;
    int s = idx >> 4;
    int x = s % 40;
    int y = (s / 40) % 26;
    int b = s / (40*26);
    int h = y - 1, w = x - 8;
    float val = 0.0f;
    if (h >= 0 && h < 24 && w >= 0 && w < 24)
        val = v[((b*16 + i)*24 + h)*24 + w];
    vpad[idx] = __float2bfloat16(val);
}

// ---------------- Kernel 3: main MFMA correlation ----------------
// 576 blocks (16 b x 12 h-pairs x 3 w-tiles), 256 threads = 4 waves.
// Wave computes C[16o x 16n], n = (hn in 2) x (wn in 8). dy-loop split across
// the 4 waves (strided), LDS reduction at the end.
__launch_bounds__(256)
__global__ void conv_main(const __hip_bfloat16* __restrict__ kt_,
                          const __hip_bfloat16* __restrict__ vpad_,
                          const float* __restrict__ bias,
                          float* __restrict__ out)
{
    __shared__ float red[4][64][4];
    const short* kt = (const short*)kt_;
    const short* vp = (const short*)vpad_;

    const int tile = blockIdx.x;
    const int b   = tile / 36;
    const int rem = tile % 36;
    const int h0  = (rem / 3) * 2;
    const int w0  = (rem % 3) * 8;

    const int tid  = threadIdx.x;
    const int lane = tid & 63;
    const int wv   = tid >> 6;
    const int n    = lane & 15;     // A: o index; B: position index
    const int g    = lane >> 4;     // k-group: k = 8g+e
    const int d    = g >> 1;        // dx sub-offset within pair
    const int ih   = (g & 1) * 8;   // i-half
    const int hn   = n >> 3;
    const int wn   = n & 7;

    f32x4 acc0 = {0.f,0.f,0.f,0.f};
    f32x4 acc1 = {0.f,0.f,0.f,0.f};

    // t = dy-index 0..24; dy = t - h0 - 1 (valid union for the h-pair).
    for (int t = wv; t < 25; t += 4) {
        const int dy47 = t - h0 + 22;            // dy + 23, in [0,46]
        const int yp   = hn + t;                 // y' = h+dy+1, in [0,25]
        // A: kt[(dy47*49 + dxi)*256 + o*16 + ih], dxi = 16 - w0 + 2p + d
        const short* ap = kt + ((long)(dy47*49 + (16 - w0 + d)))*256 + n*16 + ih;
        // B: vp[((b*26+y')*40 + x')*16 + i], x' = wn + d + 2p
        const short* bp = vp + ((long)((b*26 + yp)*40 + (wn + d)))*16 + ih;
        #pragma unroll
        for (int p = 0; p < 16; ++p) {
            bf16x8 av = *(const bf16x8*)(ap + p*512);   // dxi += 2 -> 512 shorts
            bf16x8 bv = *(const bf16x8*)(bp + p*32);    // x'  += 2 -> 32 shorts
            if (p & 1) acc1 = __builtin_amdgcn_mfma_f32_16x16x32_bf16(av, bv, acc1, 0, 0, 0);
            else       acc0 = __builtin_amdgcn_mfma_f32_16x16x32_bf16(av, bv, acc0, 0, 0, 0);
        }
    }
    acc0 += acc1;

    red[wv][lane][0] = acc0[0];
    red[wv][lane][1] = acc0[1];
    red[wv][lane][2] = acc0[2];
    red[wv][lane][3] = acc0[3];
    __syncthreads();

    if (wv == 0) {
        float s0 = acc0[0] + red[1][lane][0] + red[2][lane][0] + red[3][lane][0];
        float s1 = acc0[1] + red[1][lane][1] + red[2][lane][1] + red[3][lane][1];
        float s2 = acc0[2] + red[1][lane][2] + red[2][lane][2] + red[3][lane][2];
        float s3 = acc0[3] + red[1][lane][3] + red[2][lane][3] + red[3][lane][3];
        const float sc = 1.0f/576.0f;
        const int h = h0 + hn, w = w0 + wn;
        float r[4] = {s0, s1, s2, s3};
        #pragma unroll
        for (int q = 0; q < 4; ++q) {
            int o = g*4 + q;                     // C row = (lane>>4)*4 + reg
            out[((b*16 + o)*24 + h)*24 + w] = r[q]*sc + bias[o];
        }
    }
}

extern "C" void kernel_launch(void* const* d_in, const int* in_sizes, int n_in,
                              void* d_out, int out_size, void* d_ws, size_t ws_size,
                              hipStream_t stream)
{
    const float* v    = (const float*)d_in[0];
    const float* w1   = (const float*)d_in[1];
    const float* b1   = (const float*)d_in[2];
    const float* w2   = (const float*)d_in[3];
    const float* b2   = (const float*)d_in[4];
    const float* bias = (const float*)d_in[5];
    float* out = (float*)d_out;

    char* ws = (char*)d_ws;
    __hip_bfloat16* kt   = (__hip_bfloat16*)ws;                       // 1,179,136 B
    __hip_bfloat16* vpad = (__hip_bfloat16*)(ws + (size_t)KT_ELEMS*2); // 532,480 B

    build_ktable<<<dim3(47), dim3(256), 0, stream>>>(w1, b1, w2, b2, kt);
    pad_v<<<dim3((VPAD_ELEMS + 255)/256), dim3(256), 0, stream>>>(v, vpad);
    conv_main<<<dim3(576), dim3(256), 0, stream>>>(kt, vpad, bias, out);
}

// Round 2
// 50.537 us; speedup vs baseline: 1.7699x; 1.7699x over previous
//
#include <hip/hip_runtime.h>
#include <hip/hip_bf16.h>

// Problem constants: B=16, Ci=16, Co=16, H=W=24, hidden=64.
// K table: K[dy47][dxi][o][i], dy47 = dy+23 in [0,47), dxi = dx+24 in [0,49)
// (dx padded one column of zeros on each side so dx-pairs never go OOB).
// v_pad: bf16 [b][y'=26][x'=40][i=16], y' = h+dy+1, x' = w+dx+d+8, zero-padded.

typedef __attribute__((ext_vector_type(8))) short bf16x8;
typedef __attribute__((ext_vector_type(4))) float f32x4;

#define KT_ELEMS (47*49*256)          // 589,568 bf16
#define VPAD_ELEMS (16*26*40*16)      // 266,240 bf16
#define NROWS (47*49)                 // 2303 (dy,dxi) rows

// ---------------- Kernel 1: build K table (fused hid + GEMM) ----------------
// 288 blocks x 256 threads; block owns 8 rows of the [2303 x 256] K GEMM.
// Phase 0: tanh tables (96 evals). Phase 1: hid tile 8x64 in LDS (2 gelu/thr).
// Phase 2: per-thread column GEMM: acc[8] += hid[r][j] * w2[c][j], LDS
// broadcast reads + contiguous float4 w2 reads. 512 FMA/thread.
__launch_bounds__(256)
__global__ void build_kt_fused(const float* __restrict__ w1, const float* __restrict__ b1,
                               const float* __restrict__ w2, const float* __restrict__ b2,
                               __hip_bfloat16* __restrict__ kt)
{
    __shared__ float ty_s[47];
    __shared__ float tx_s[49];
    __shared__ float hid_s[8][64];
    const int tid = threadIdx.x;
    const int r0  = blockIdx.x * 8;

    if (tid < 47)               ty_s[tid]      = tanhf((float)(tid - 23) * (1.0f/6.0f));
    if (tid >= 64 && tid < 113) tx_s[tid - 64] = tanhf((float)(tid - 64 - 24) * (1.0f/6.0f));
    __syncthreads();

    #pragma unroll
    for (int k = 0; k < 2; ++k) {
        int idx = k*256 + tid;          // 0..511
        int rr  = idx >> 6;             // 0..7
        int j   = idx & 63;
        int r   = r0 + rr;
        if (r >= NROWS) r = NROWS - 1;  // clamp (last block tail)
        int dy47 = r / 49;
        int dxi  = r % 49;
        float x = ty_s[dy47]*w1[2*j] + tx_s[dxi]*w1[2*j+1] + b1[j];
        hid_s[rr][j] = 0.5f*x*(1.0f + erff(x*0.70710678118f));   // exact gelu
    }
    __syncthreads();

    const int c = tid;                  // output column (o*16+i)
    float acc[8];
    const float bb = b2[c];
    #pragma unroll
    for (int r = 0; r < 8; ++r) acc[r] = bb;

    const float4* w2v = (const float4*)w2;      // w2[c][j], rows contiguous
    #pragma unroll
    for (int jv = 0; jv < 16; ++jv) {
        float4 wv = w2v[c*16 + jv];
        #pragma unroll
        for (int e = 0; e < 4; ++e) {
            float we = ((const float*)&wv)[e];
            int j = jv*4 + e;
            #pragma unroll
            for (int r = 0; r < 8; ++r)
                acc[r] += hid_s[r][j] * we;     // LDS broadcast (same addr all lanes)
        }
    }

    #pragma unroll
    for (int rr = 0; rr < 8; ++rr) {
        int r = r0 + rr;
        if (r >= NROWS) break;
        int dxi = r % 49;
        float val = (dxi == 0 || dxi == 48) ? 0.0f : acc[rr];   // OOB pad columns
        kt[r*256 + c] = __float2bfloat16(val);
    }
}

// ---------------- Kernel 2: pad + transpose v to bf16 ----------------
__global__ void pad_v(const float* __restrict__ v, __hip_bfloat16* __restrict__ vpad)
{
    int idx = blockIdx.x*256 + threadIdx.x;      // [b][y][x][i]
    if (idx >= VPAD_ELEMS) return;
    int i = idx & 15;
    int s = idx >> 4;
    int x = s % 40;
    int y = (s / 40) % 26;
    int b = s / (40*26);
    int h = y - 1, w = x - 8;
    float val = 0.0f;
    if (h >= 0 && h < 24 && w >= 0 && w < 24)
        val = v[((b*16 + i)*24 + h)*24 + w];
    vpad[idx] = __float2bfloat16(val);
}

// ---------------- Kernel 3: main MFMA correlation ----------------
// 576 blocks (16 b x 12 h-pairs x 3 w-tiles), 256 threads = 4 waves.
// Wave computes C[16o x 16n], n = (hn in 2) x (wn in 8). dy-loop split across
// the 4 waves (strided), LDS reduction at the end.
__launch_bounds__(256)
__global__ void conv_main(const __hip_bfloat16* __restrict__ kt_,
                          const __hip_bfloat16* __restrict__ vpad_,
                          const float* __restrict__ bias,
                          float* __restrict__ out)
{
    __shared__ float red[4][64][4];
    const short* kt = (const short*)kt_;
    const short* vp = (const short*)vpad_;

    const int tile = blockIdx.x;
    const int b   = tile / 36;
    const int rem = tile % 36;
    const int h0  = (rem / 3) * 2;
    const int w0  = (rem % 3) * 8;

    const int tid  = threadIdx.x;
    const int lane = tid & 63;
    const int wv   = tid >> 6;
    const int n    = lane & 15;     // A: o index; B: position index
    const int g    = lane >> 4;     // k-group: k = 8g+e
    const int d    = g >> 1;        // dx sub-offset within pair
    const int ih   = (g & 1) * 8;   // i-half
    const int hn   = n >> 3;
    const int wn   = n & 7;

    f32x4 acc0 = {0.f,0.f,0.f,0.f};
    f32x4 acc1 = {0.f,0.f,0.f,0.f};

    // t = dy-index 0..24; dy = t - h0 - 1 (valid union for the h-pair).
    for (int t = wv; t < 25; t += 4) {
        const int dy47 = t - h0 + 22;            // dy + 23, in [0,46]
        const int yp   = hn + t;                 // y' = h+dy+1, in [0,25]
        // A: kt[(dy47*49 + dxi)*256 + o*16 + ih], dxi = 16 - w0 + 2p + d
        const short* ap = kt + ((long)(dy47*49 + (16 - w0 + d)))*256 + n*16 + ih;
        // B: vp[((b*26+y')*40 + x')*16 + i], x' = wn + d + 2p
        const short* bp = vp + ((long)((b*26 + yp)*40 + (wn + d)))*16 + ih;
        #pragma unroll
        for (int p = 0; p < 16; ++p) {
            bf16x8 av = *(const bf16x8*)(ap + p*512);   // dxi += 2 -> 512 shorts
            bf16x8 bv = *(const bf16x8*)(bp + p*32);    // x'  += 2 -> 32 shorts
            if (p & 1) acc1 = __builtin_amdgcn_mfma_f32_16x16x32_bf16(av, bv, acc1, 0, 0, 0);
            else       acc0 = __builtin_amdgcn_mfma_f32_16x16x32_bf16(av, bv, acc0, 0, 0, 0);
        }
    }
    acc0 += acc1;

    red[wv][lane][0] = acc0[0];
    red[wv][lane][1] = acc0[1];
    red[wv][lane][2] = acc0[2];
    red[wv][lane][3] = acc0[3];
    __syncthreads();

    if (wv == 0) {
        float s0 = acc0[0] + red[1][lane][0] + red[2][lane][0] + red[3][lane][0];
        float s1 = acc0[1] + red[1][lane][1] + red[2][lane][1] + red[3][lane][1];
        float s2 = acc0[2] + red[1][lane][2] + red[2][lane][2] + red[3][lane][2];
        float s3 = acc0[3] + red[1][lane][3] + red[2][lane][3] + red[3][lane][3];
        const float sc = 1.0f/576.0f;
        const int h = h0 + hn, w = w0 + wn;
        float r[4] = {s0, s1, s2, s3};
        #pragma unroll
        for (int q = 0; q < 4; ++q) {
            int o = g*4 + q;                     // C row = (lane>>4)*4 + reg
            out[((b*16 + o)*24 + h)*24 + w] = r[q]*sc + bias[o];
        }
    }
}

extern "C" void kernel_launch(void* const* d_in, const int* in_sizes, int n_in,
                              void* d_out, int out_size, void* d_ws, size_t ws_size,
                              hipStream_t stream)
{
    const float* v    = (const float*)d_in[0];
    const float* w1   = (const float*)d_in[1];
    const float* b1   = (const float*)d_in[2];
    const float* w2   = (const float*)d_in[3];
    const float* b2   = (const float*)d_in[4];
    const float* bias = (const float*)d_in[5];
    float* out = (float*)d_out;

    char* ws = (char*)d_ws;
    __hip_bfloat16* kt   = (__hip_bfloat16*)ws;                        // 1,179,136 B
    __hip_bfloat16* vpad = (__hip_bfloat16*)(ws + (size_t)KT_ELEMS*2); // 532,480 B

    build_kt_fused<<<dim3((NROWS + 7)/8), dim3(256), 0, stream>>>(w1, b1, w2, b2, kt);
    pad_v<<<dim3((VPAD_ELEMS + 255)/256), dim3(256), 0, stream>>>(v, vpad);
    conv_main<<<dim3(576), dim3(256), 0, stream>>>(kt, vpad, bias, out);
}

// Round 3
// 44.537 us; speedup vs baseline: 2.0084x; 1.1347x over previous
//
#include <hip/hip_runtime.h>
#include <hip/hip_bf16.h>

// B=16, Ci=16, Co=16, H=W=24, hidden=64.
// kt:   K[dy47][dxi][o][i] bf16, dy47=dy+23 in [0,47), dxi=dx+24 in [0,49)
//       (dxi cols 0 and 48 zeroed so dx-pairs never need bounds checks).
// vpad: bf16 [b][y'=40][x'=40][i=16], y'=h+8, x'=w+8, zero-padded halo.
// conv_part: 576 blocks = (b16, hq6 (4h), ww3 (8w), th2 (dy-half)); 4 waves.
//   Wave tile: 16o x 32 pos (4h x 8w) = 2 MFMA C-tiles sharing each A frag.
//   dy split 8 ways (th*? + wave), partials -> ws; combine adds halves + bias.

typedef __attribute__((ext_vector_type(8))) short bf16x8;
typedef __attribute__((ext_vector_type(4))) float f32x4;

#define KT_ELEMS (47*49*256)          // 589,568 bf16
#define VPAD_ELEMS (16*40*40*16)      // 409,600 bf16
#define NROWS (47*49)                 // 2303 MLP rows
#define OUT_ELEMS (16*16*24*24)       // 147,456

// ---------------- Kernel 1: build K table (fused hid + GEMM) ----------------
__launch_bounds__(256)
__global__ void build_kt_fused(const float* __restrict__ w1, const float* __restrict__ b1,
                               const float* __restrict__ w2, const float* __restrict__ b2,
                               __hip_bfloat16* __restrict__ kt)
{
    __shared__ float ty_s[47];
    __shared__ float tx_s[49];
    __shared__ float hid_s[8][64];
    const int tid = threadIdx.x;
    const int r0  = blockIdx.x * 8;

    if (tid < 47)               ty_s[tid]      = tanhf((float)(tid - 23) * (1.0f/6.0f));
    if (tid >= 64 && tid < 113) tx_s[tid - 64] = tanhf((float)(tid - 64 - 24) * (1.0f/6.0f));
    __syncthreads();

    #pragma unroll
    for (int k = 0; k < 2; ++k) {
        int idx = k*256 + tid;
        int rr  = idx >> 6;
        int j   = idx & 63;
        int r   = r0 + rr;
        if (r >= NROWS) r = NROWS - 1;
        int dy47 = r / 49;
        int dxi  = r % 49;
        float x = ty_s[dy47]*w1[2*j] + tx_s[dxi]*w1[2*j+1] + b1[j];
        hid_s[rr][j] = 0.5f*x*(1.0f + erff(x*0.70710678118f));
    }
    __syncthreads();

    const int c = tid;
    float acc[8];
    const float bb = b2[c];
    #pragma unroll
    for (int r = 0; r < 8; ++r) acc[r] = bb;

    const float4* w2v = (const float4*)w2;
    #pragma unroll
    for (int jv = 0; jv < 16; ++jv) {
        float4 wv = w2v[c*16 + jv];
        #pragma unroll
        for (int e = 0; e < 4; ++e) {
            float we = ((const float*)&wv)[e];
            int j = jv*4 + e;
            #pragma unroll
            for (int r = 0; r < 8; ++r)
                acc[r] += hid_s[r][j] * we;
        }
    }

    #pragma unroll
    for (int rr = 0; rr < 8; ++rr) {
        int r = r0 + rr;
        if (r >= NROWS) break;
        int dxi = r % 49;
        float val = (dxi == 0 || dxi == 48) ? 0.0f : acc[rr];
        kt[r*256 + c] = __float2bfloat16(val);
    }
}

// ---------------- Kernel 2: pad + transpose v to bf16 ----------------
__global__ void pad_v(const float* __restrict__ v, __hip_bfloat16* __restrict__ vpad)
{
    int idx = blockIdx.x*256 + threadIdx.x;      // [b][y'][x'][i]
    if (idx >= VPAD_ELEMS) return;
    int i = idx & 15;
    int s = idx >> 4;
    int x = s % 40;
    int y = (s / 40) % 40;
    int b = s / 1600;
    int h = y - 8, w = x - 8;
    float val = 0.0f;
    if (h >= 0 && h < 24 && w >= 0 && w < 24)
        val = v[((b*16 + i)*24 + h)*24 + w];
    vpad[idx] = __float2bfloat16(val);
}

// ---------------- Kernel 3: main MFMA correlation (partials) ----------------
// Wave: 2 C-tiles (q=0,1), A frag shared. k = (d in 2, i in 16) per MFMA.
__launch_bounds__(256)
__global__ void conv_part(const __hip_bfloat16* __restrict__ kt_,
                          const __hip_bfloat16* __restrict__ vpad_,
                          float* __restrict__ part)
{
    __shared__ float red[4][2][64][4];   // 8 KB
    const short* kt = (const short*)kt_;
    const short* vp = (const short*)vpad_;

    const int tile = blockIdx.x;         // b*36 + hq*6 + ww*2 + th
    const int b   = tile / 36;
    const int rem = tile % 36;
    const int hq  = rem / 6;
    const int sub = rem % 6;
    const int ww  = sub >> 1;
    const int th  = sub & 1;
    const int h0  = hq * 4;
    const int w0  = ww * 8;

    const int tid  = threadIdx.x;
    const int lane = tid & 63;
    const int wv   = tid >> 6;
    const int n    = lane & 15;          // A: o row; B: position col
    const int g    = lane >> 4;          // k-group
    const int d    = g >> 1;             // dx sub-offset
    const int ih   = (g & 1) * 8;        // i-half
    const int hn   = n >> 3;
    const int wn   = n & 7;

    f32x4 a00 = {0,0,0,0}, a01 = {0,0,0,0}, a10 = {0,0,0,0}, a11 = {0,0,0,0};

    // dy = t - h0 - 3, t in [0,27); covers union of dy windows for 4 h rows.
    const int tt = wv*2 + th;            // 8-way split of t
    for (int t = tt; t < 27; t += 8) {
        const int dy47 = t - h0 + 20;                    // in [0,46]
        const short* ap  = kt + ((long)(dy47*49 + (16 - w0 + d)))*256 + n*16 + ih;
        const int ypb  = t + hn + 5;                     // y'(q) = ypb + 2q, in [5,34]
        const short* bp0 = vp + ((long)((b*40 + ypb)*40 + (wn + d)))*16 + ih;
        const short* bp1 = bp0 + 2*40*16;                // q=1: +2 rows
        #pragma unroll
        for (int p = 0; p < 16; ++p) {
            bf16x8 av  = *(const bf16x8*)(ap  + p*512);  // dxi += 2
            bf16x8 bv0 = *(const bf16x8*)(bp0 + p*32);   // x'  += 2
            bf16x8 bv1 = *(const bf16x8*)(bp1 + p*32);
            if (p & 1) {
                a01 = __builtin_amdgcn_mfma_f32_16x16x32_bf16(av, bv0, a01, 0, 0, 0);
                a11 = __builtin_amdgcn_mfma_f32_16x16x32_bf16(av, bv1, a11, 0, 0, 0);
            } else {
                a00 = __builtin_amdgcn_mfma_f32_16x16x32_bf16(av, bv0, a00, 0, 0, 0);
                a10 = __builtin_amdgcn_mfma_f32_16x16x32_bf16(av, bv1, a10, 0, 0, 0);
            }
        }
    }
    a00 += a01;                           // q=0 total
    a10 += a11;                           // q=1 total

    #pragma unroll
    for (int e = 0; e < 4; ++e) { red[wv][0][lane][e] = a00[e]; red[wv][1][lane][e] = a10[e]; }
    __syncthreads();

    if (wv == 0) {
        #pragma unroll
        for (int q = 0; q < 2; ++q) {
            float s[4];
            #pragma unroll
            for (int e = 0; e < 4; ++e)
                s[e] = red[0][q][lane][e] + red[1][q][lane][e]
                     + red[2][q][lane][e] + red[3][q][lane][e];
            const int h = h0 + q*2 + hn;
            const int w = w0 + wn;
            #pragma unroll
            for (int e = 0; e < 4; ++e) {
                int o = g*4 + e;          // C row = (lane>>4)*4 + reg
                part[(size_t)th*OUT_ELEMS + ((b*16 + o)*24 + h)*24 + w] = s[e];
            }
        }
    }
}

// ---------------- Kernel 4: combine halves + bias ----------------
__global__ void combine(const float* __restrict__ part, const float* __restrict__ bias,
                        float* __restrict__ out)
{
    int idx = blockIdx.x*256 + threadIdx.x;   // [b][o][h][w]
    if (idx >= OUT_ELEMS) return;
    int o = (idx / 576) & 15;
    out[idx] = (part[idx] + part[OUT_ELEMS + idx]) * (1.0f/576.0f) + bias[o];
}

extern "C" void kernel_launch(void* const* d_in, const int* in_sizes, int n_in,
                              void* d_out, int out_size, void* d_ws, size_t ws_size,
                              hipStream_t stream)
{
    const float* v    = (const float*)d_in[0];
    const float* w1   = (const float*)d_in[1];
    const float* b1   = (const float*)d_in[2];
    const float* w2   = (const float*)d_in[3];
    const float* b2   = (const float*)d_in[4];
    const float* bias = (const float*)d_in[5];
    float* out = (float*)d_out;

    char* ws = (char*)d_ws;
    __hip_bfloat16* kt   = (__hip_bfloat16*)ws;                        // 1,179,136 B
    __hip_bfloat16* vpad = (__hip_bfloat16*)(ws + (size_t)KT_ELEMS*2); //   819,200 B
    float* part = (float*)(ws + (size_t)KT_ELEMS*2 + (size_t)VPAD_ELEMS*2); // 1,179,648 B

    build_kt_fused<<<dim3((NROWS + 7)/8), dim3(256), 0, stream>>>(w1, b1, w2, b2, kt);
    pad_v<<<dim3((VPAD_ELEMS + 255)/256), dim3(256), 0, stream>>>(v, vpad);
    conv_part<<<dim3(576), dim3(256), 0, stream>>>(kt, vpad, part);
    combine<<<dim3((OUT_ELEMS + 255)/256), dim3(256), 0, stream>>>(part, bias, out);
}

// Round 7
// 30.475 us; speedup vs baseline: 2.9351x; 1.4614x over previous
//
#include <hip/hip_runtime.h>
#include <hip/hip_bf16.h>

// B=16, Ci=16, Co=16, H=W=24, hidden=64.
// kt:    K[dy47][dxi][o][i] bf16; dy47 = dy+23 in [0,47), dxi = dx+24 in [0,49).
// vpad2: bf16 [y'=40][x'=40][b=16][i=16], y'=h+8, x'=w+8, zero halo.
// conv_part: grid (w24, hg6, oct7), 256 thr = 4 waves. Wave t = oct*4+wv picks
//   one dy (dy = t - h0 - 3, t<27). C-tile = 16o x 16b; 4 h-rows per wave share
//   each A-frag; dx window exact (12 dx-pairs). Waves LDS-reduce; 7 octet
//   partials in ws; combine sums octets, scales, adds bias, transposed write.

typedef __attribute__((ext_vector_type(8))) short bf16x8;
typedef __attribute__((ext_vector_type(4))) float f32x4;

#define KT_ELEMS (47*49*256)          // 589,568 bf16
#define VPAD2_ELEMS (40*40*256)       // 409,600 bf16
#define NROWS (47*49)                 // 2303 MLP rows
#define NPOS 576                      // 24*24 output positions
#define NOCT 7                        // dy octets (7*4 = 28 >= 27)

// ---------------- Kernel 1: build K table (fused hid + GEMM) ----------------
__launch_bounds__(256)
__global__ void build_kt_fused(const float* __restrict__ w1, const float* __restrict__ b1,
                               const float* __restrict__ w2, const float* __restrict__ b2,
                               __hip_bfloat16* __restrict__ kt)
{
    __shared__ float ty_s[47];
    __shared__ float tx_s[49];
    __shared__ float hid_s[8][64];
    const int tid = threadIdx.x;
    const int r0  = blockIdx.x * 8;

    if (tid < 47)               ty_s[tid]      = tanhf((float)(tid - 23) * (1.0f/6.0f));
    if (tid >= 64 && tid < 113) tx_s[tid - 64] = tanhf((float)(tid - 64 - 24) * (1.0f/6.0f));
    __syncthreads();

    #pragma unroll
    for (int k = 0; k < 2; ++k) {
        int idx = k*256 + tid;
        int rr  = idx >> 6;
        int j   = idx & 63;
        int r   = r0 + rr;
        if (r >= NROWS) r = NROWS - 1;
        int dy47 = r / 49;
        int dxi  = r % 49;
        float x = ty_s[dy47]*w1[2*j] + tx_s[dxi]*w1[2*j+1] + b1[j];
        hid_s[rr][j] = 0.5f*x*(1.0f + erff(x*0.70710678118f));
    }
    __syncthreads();

    const int c = tid;
    float acc[8];
    const float bb = b2[c];
    #pragma unroll
    for (int r = 0; r < 8; ++r) acc[r] = bb;

    const float4* w2v = (const float4*)w2;
    #pragma unroll
    for (int jv = 0; jv < 16; ++jv) {
        float4 wv = w2v[c*16 + jv];
        #pragma unroll
        for (int e = 0; e < 4; ++e) {
            float we = ((const float*)&wv)[e];
            int j = jv*4 + e;
            #pragma unroll
            for (int r = 0; r < 8; ++r)
                acc[r] += hid_s[r][j] * we;
        }
    }

    #pragma unroll
    for (int rr = 0; rr < 8; ++rr) {
        int r = r0 + rr;
        if (r >= NROWS) break;
        kt[r*256 + c] = __float2bfloat16(acc[rr]);
    }
}

// ---------------- Kernel 2: pad + transpose v -> vpad2 [y][x][b][i] ----------
__global__ void pad_v2(const float* __restrict__ v, __hip_bfloat16* __restrict__ vpad)
{
    int idx = blockIdx.x*256 + threadIdx.x;
    if (idx >= VPAD2_ELEMS) return;
    int i = idx & 15;
    int b = (idx >> 4) & 15;
    int s = idx >> 8;                 // y*40 + x
    int x = s % 40;
    int y = s / 40;
    int h = y - 8, w = x - 8;
    float val = 0.0f;
    if (h >= 0 && h < 24 && w >= 0 && w < 24)
        val = v[((b*16 + i)*24 + h)*24 + w];
    vpad[idx] = __float2bfloat16(val);
}

// ---------------- Kernel 3: main MFMA correlation (octet partials) ----------
__launch_bounds__(256)
__global__ void conv_part(const __hip_bfloat16* __restrict__ kt_,
                          const __hip_bfloat16* __restrict__ vpad_,
                          float* __restrict__ part)
{
    __shared__ f32x4 red[4][4][64];   // [src wave][h-row][lane], 16 KB
    const short* kt = (const short*)kt_;
    const short* vp = (const short*)vpad_;

    const int w   = blockIdx.x;       // 0..23
    const int hg  = blockIdx.y;       // 0..5
    const int oct = blockIdx.z;       // 0..6
    const int h0  = hg * 4;

    const int tid  = threadIdx.x;
    const int lane = tid & 63;
    const int wv   = tid >> 6;
    const int n    = lane & 15;       // A: o row; B: b col
    const int g    = lane >> 4;       // k-group
    const int d    = g >> 1;          // dx sub-offset within pair
    const int ih   = (g & 1) * 8;     // i-half

    const int t = oct*4 + wv;         // dy index; dy = t - h0 - 3, valid t<27

    f32x4 acc[4];
    #pragma unroll
    for (int hh = 0; hh < 4; ++hh) acc[hh] = (f32x4){0.f,0.f,0.f,0.f};

    if (t < 27) {
        const int dy47 = t - h0 + 20;                       // in [0,46]
        // A: kt[(dy47*49 + dxi)*256 + o*16 + ih], dxi = 24 - w + 2*dxp + d
        const short* ap = kt + ((long)(dy47*49 + (24 - w + d)))*256 + n*16 + ih;
        // B: vp[((y')*40 + x')*256 + b*16 + ih], y' = t+hh+5, x' = 8 + 2*dxp + d
        const short* bp = vp + ((long)((t + 5)*40 + (8 + d)))*256 + n*16 + ih;
        #pragma unroll
        for (int dxp = 0; dxp < 12; ++dxp) {
            bf16x8 av = *(const bf16x8*)(ap + dxp*512);
            #pragma unroll
            for (int hh = 0; hh < 4; ++hh) {
                bf16x8 bv = *(const bf16x8*)(bp + hh*10240 + dxp*512);  // +y' row = 40*256
                acc[hh] = __builtin_amdgcn_mfma_f32_16x16x32_bf16(av, bv, acc[hh], 0, 0, 0);
            }
        }
    }

    #pragma unroll
    for (int hh = 0; hh < 4; ++hh) red[wv][hh][lane] = acc[hh];
    __syncthreads();

    // wave wv owns output row h = h0 + wv; sum the 4 source waves (4 dy's)
    f32x4 s = red[0][wv][lane];
    s += red[1][wv][lane];
    s += red[2][wv][lane];
    s += red[3][wv][lane];

    const int p = (h0 + wv)*24 + w;
    // part layout: [oct][p][b*16 + o], o = g*4+e contiguous per lane -> f32x4
    float* dst = part + ((size_t)oct*NPOS + p)*256 + (n*16 + g*4);
    *(f32x4*)dst = s;
}

// ---------------- Kernel 4: combine octets + scale + bias (transpose) -------
__launch_bounds__(256)
__global__ void combine(const float* __restrict__ part, const float* __restrict__ bias,
                        float* __restrict__ out)
{
    __shared__ float lds[16][257];
    const int tid = threadIdx.x;
    const int p0  = blockIdx.x * 16;

    #pragma unroll
    for (int pp = 0; pp < 16; ++pp) {
        float s = 0.f;
        #pragma unroll
        for (int oct = 0; oct < NOCT; ++oct)
            s += part[((size_t)oct*NPOS + p0 + pp)*256 + tid];
        lds[pp][tid] = s;
    }
    __syncthreads();

    const int pp = tid & 15;
    const int g  = tid >> 4;          // 0..15 across the block
    const float sc = 1.0f/576.0f;
    #pragma unroll
    for (int cc = 0; cc < 16; ++cc) {
        int c2 = cc*16 + g;           // c2 = b*16 + o
        out[(size_t)c2*576 + p0 + pp] = lds[pp][c2]*sc + bias[c2 & 15];
    }
}

extern "C" void kernel_launch(void* const* d_in, const int* in_sizes, int n_in,
                              void* d_out, int out_size, void* d_ws, size_t ws_size,
                              hipStream_t stream)
{
    const float* v    = (const float*)d_in[0];
    const float* w1   = (const float*)d_in[1];
    const float* b1   = (const float*)d_in[2];
    const float* w2   = (const float*)d_in[3];
    const float* b2   = (const float*)d_in[4];
    const float* bias = (const float*)d_in[5];
    float* out = (float*)d_out;

    char* ws = (char*)d_ws;
    __hip_bfloat16* kt   = (__hip_bfloat16*)ws;                          // 1,179,136 B
    __hip_bfloat16* vpad = (__hip_bfloat16*)(ws + (size_t)KT_ELEMS*2);   //   819,200 B
    float* part = (float*)(ws + (size_t)KT_ELEMS*2 + (size_t)VPAD2_ELEMS*2); // 4,128,768 B

    build_kt_fused<<<dim3((NROWS + 7)/8), dim3(256), 0, stream>>>(w1, b1, w2, b2, kt);
    pad_v2<<<dim3((VPAD2_ELEMS + 255)/256), dim3(256), 0, stream>>>(v, vpad);
    conv_part<<<dim3(24, 6, NOCT), dim3(256), 0, stream>>>(kt, vpad, part);
    combine<<<dim3(NPOS/16), dim3(256), 0, stream>>>(part, bias, out);
}

// Round 8
// 28.077 us; speedup vs baseline: 3.1858x; 1.0854x over previous
//
#include <hip/hip_runtime.h>
#include <hip/hip_bf16.h>

// B=16, Ci=16, Co=16, H=W=24, hidden=64.
// kt:    K[dy47][dxi][o][i] bf16; dy47 = dy+23 in [0,47), dxi = dx+24 in [0,49).
// vpad2: bf16 [y'=40][x'=40][b=16][i=16], y'=h+8, x'=w+8, zero halo.
// conv_part: grid (w24, hg6, oct7), 512 thr = 8 waves: wave = (tq 0..3, dxh 0..1).
//   t = oct*4+tq picks dy (dy = t - h0 - 3, t<27); wave does 6 dxp x 4 hh MFMAs.
//   C-tile = 16o x 16b. 8-wave LDS reduce -> 7 octet partials; combine sums.

typedef __attribute__((ext_vector_type(8))) short bf16x8;
typedef __attribute__((ext_vector_type(4))) float f32x4;

#define KT_ELEMS (47*49*256)          // 589,568 bf16
#define VPAD2_ELEMS (40*40*256)       // 409,600 bf16
#define NROWS (47*49)                 // 2303 MLP rows
#define NPOS 576                      // 24*24 output positions
#define NOCT 7                        // dy octets (7*4 = 28 >= 27)
#define PREP_BUILD_BLOCKS 288         // ceil(2303/8)
#define PREP_PAD_BLOCKS (VPAD2_ELEMS/256)   // 1600

// ---------------- Kernel 1: prep = build K table + pad v (fused grid) -------
__launch_bounds__(256)
__global__ void prep(const float* __restrict__ v,
                     const float* __restrict__ w1, const float* __restrict__ b1,
                     const float* __restrict__ w2, const float* __restrict__ b2,
                     __hip_bfloat16* __restrict__ kt, __hip_bfloat16* __restrict__ vpad)
{
    const int tid = threadIdx.x;

    if (blockIdx.x >= PREP_BUILD_BLOCKS) {
        // ---- pad part: vpad2[y][x][b][i] ----
        int idx = (blockIdx.x - PREP_BUILD_BLOCKS)*256 + tid;
        if (idx >= VPAD2_ELEMS) return;
        int i = idx & 15;
        int b = (idx >> 4) & 15;
        int s = idx >> 8;             // y*40 + x
        int x = s % 40;
        int y = s / 40;
        int h = y - 8, w = x - 8;
        float val = 0.0f;
        if (h >= 0 && h < 24 && w >= 0 && w < 24)
            val = v[((b*16 + i)*24 + h)*24 + w];
        vpad[idx] = __float2bfloat16(val);
        return;
    }

    // ---- build part: 8 rows of the [2303 x 256] K GEMM per block ----
    __shared__ float ty_s[47];
    __shared__ float tx_s[49];
    __shared__ float hid_s[8][64];
    const int r0 = blockIdx.x * 8;

    if (tid < 47)               ty_s[tid]      = tanhf((float)(tid - 23) * (1.0f/6.0f));
    if (tid >= 64 && tid < 113) tx_s[tid - 64] = tanhf((float)(tid - 64 - 24) * (1.0f/6.0f));
    __syncthreads();

    #pragma unroll
    for (int k = 0; k < 2; ++k) {
        int idx = k*256 + tid;
        int rr  = idx >> 6;
        int j   = idx & 63;
        int r   = r0 + rr;
        if (r >= NROWS) r = NROWS - 1;
        int dy47 = r / 49;
        int dxi  = r % 49;
        float x = ty_s[dy47]*w1[2*j] + tx_s[dxi]*w1[2*j+1] + b1[j];
        hid_s[rr][j] = 0.5f*x*(1.0f + erff(x*0.70710678118f));
    }
    __syncthreads();

    const int c = tid;
    float acc[8];
    const float bb = b2[c];
    #pragma unroll
    for (int r = 0; r < 8; ++r) acc[r] = bb;

    const float4* w2v = (const float4*)w2;
    #pragma unroll
    for (int jv = 0; jv < 16; ++jv) {
        float4 wv = w2v[c*16 + jv];
        #pragma unroll
        for (int e = 0; e < 4; ++e) {
            float we = ((const float*)&wv)[e];
            int j = jv*4 + e;
            #pragma unroll
            for (int r = 0; r < 8; ++r)
                acc[r] += hid_s[r][j] * we;
        }
    }

    #pragma unroll
    for (int rr = 0; rr < 8; ++rr) {
        int r = r0 + rr;
        if (r >= NROWS) break;
        kt[r*256 + c] = __float2bfloat16(acc[rr]);
    }
}

// ---------------- Kernel 2: main MFMA correlation (octet partials) ----------
// 8 waves: wv = tq + 4*dxh. Wave does 6 dxp x 4 hh MFMAs on one dy.
// __launch_bounds__(512, 8): 8 waves/EU -> 4 blocks/CU (32 waves/CU), VGPR<=64.
__launch_bounds__(512, 8)
__global__ void conv_part(const __hip_bfloat16* __restrict__ kt_,
                          const __hip_bfloat16* __restrict__ vpad_,
                          float* __restrict__ part)
{
    __shared__ f32x4 red[8][4][64];   // [src wave][h-row][lane], 32 KB
    const short* kt = (const short*)kt_;
    const short* vp = (const short*)vpad_;

    const int w   = blockIdx.x;       // 0..23
    const int hg  = blockIdx.y;       // 0..5
    const int oct = blockIdx.z;       // 0..6
    const int h0  = hg * 4;

    const int tid  = threadIdx.x;
    const int lane = tid & 63;
    const int wv   = tid >> 6;        // 0..7
    const int tq   = wv & 3;
    const int dxh  = wv >> 2;         // dx-half: dxp = dxh*6 + p
    const int n    = lane & 15;       // A: o row; B: b col
    const int g    = lane >> 4;       // k-group
    const int d    = g >> 1;          // dx sub-offset within pair
    const int ih   = (g & 1) * 8;     // i-half

    const int t = oct*4 + tq;         // dy index; dy = t - h0 - 3, valid t<27

    f32x4 acc[4];
    #pragma unroll
    for (int hh = 0; hh < 4; ++hh) acc[hh] = (f32x4){0.f,0.f,0.f,0.f};

    if (t < 27) {
        const int dy47 = t - h0 + 20;                       // in [0,46]
        // A: kt[(dy47*49 + dxi)*256 + o*16 + ih], dxi = 24 - w + 12*dxh + 2p + d
        const short* ap = kt + ((long)(dy47*49 + (24 - w + 12*dxh + d)))*256 + n*16 + ih;
        // B: vp[(y'*40 + x')*256 + b*16 + ih], y' = t+hh+5, x' = 8 + 12*dxh + 2p + d
        const short* bp = vp + ((long)((t + 5)*40 + (8 + 12*dxh + d)))*256 + n*16 + ih;
        #pragma unroll
        for (int p = 0; p < 6; ++p) {
            bf16x8 av = *(const bf16x8*)(ap + p*512);
            #pragma unroll
            for (int hh = 0; hh < 4; ++hh) {
                bf16x8 bv = *(const bf16x8*)(bp + hh*10240 + p*512);  // +y' row = 40*256
                acc[hh] = __builtin_amdgcn_mfma_f32_16x16x32_bf16(av, bv, acc[hh], 0, 0, 0);
            }
        }
    }

    #pragma unroll
    for (int hh = 0; hh < 4; ++hh) red[wv][hh][lane] = acc[hh];
    __syncthreads();

    // waves 0..3: wave wv owns output row h = h0 + wv; sum the 8 sources
    if (wv < 4) {
        f32x4 s = red[0][wv][lane];
        #pragma unroll
        for (int src = 1; src < 8; ++src) s += red[src][wv][lane];

        const int p = (h0 + wv)*24 + w;
        // part layout: [oct][p][b*16 + o], o = g*4+e contiguous per lane -> f32x4
        float* dst = part + ((size_t)oct*NPOS + p)*256 + (n*16 + g*4);
        *(f32x4*)dst = s;
    }
}

// ---------------- Kernel 3: combine octets + scale + bias (transpose) -------
__launch_bounds__(256)
__global__ void combine(const float* __restrict__ part, const float* __restrict__ bias,
                        float* __restrict__ out)
{
    __shared__ float lds[16][257];
    const int tid = threadIdx.x;
    const int p0  = blockIdx.x * 16;

    #pragma unroll
    for (int pp = 0; pp < 16; ++pp) {
        float s = 0.f;
        #pragma unroll
        for (int oct = 0; oct < NOCT; ++oct)
            s += part[((size_t)oct*NPOS + p0 + pp)*256 + tid];
        lds[pp][tid] = s;
    }
    __syncthreads();

    const int pp = tid & 15;
    const int g  = tid >> 4;          // 0..15 across the block
    const float sc = 1.0f/576.0f;
    #pragma unroll
    for (int cc = 0; cc < 16; ++cc) {
        int c2 = cc*16 + g;           // c2 = b*16 + o
        out[(size_t)c2*576 + p0 + pp] = lds[pp][c2]*sc + bias[c2 & 15];
    }
}

extern "C" void kernel_launch(void* const* d_in, const int* in_sizes, int n_in,
                              void* d_out, int out_size, void* d_ws, size_t ws_size,
                              hipStream_t stream)
{
    const float* v    = (const float*)d_in[0];
    const float* w1   = (const float*)d_in[1];
    const float* b1   = (const float*)d_in[2];
    const float* w2   = (const float*)d_in[3];
    const float* b2   = (const float*)d_in[4];
    const float* bias = (const float*)d_in[5];
    float* out = (float*)d_out;

    char* ws = (char*)d_ws;
    __hip_bfloat16* kt   = (__hip_bfloat16*)ws;                          // 1,179,136 B
    __hip_bfloat16* vpad = (__hip_bfloat16*)(ws + (size_t)KT_ELEMS*2);   //   819,200 B
    float* part = (float*)(ws + (size_t)KT_ELEMS*2 + (size_t)VPAD2_ELEMS*2); // 4,128,768 B

    prep<<<dim3(PREP_BUILD_BLOCKS + PREP_PAD_BLOCKS), dim3(256), 0, stream>>>(
        v, w1, b1, w2, b2, kt, vpad);
    conv_part<<<dim3(24, 6, NOCT), dim3(512), 0, stream>>>(kt, vpad, part);
    combine<<<dim3(NPOS/16), dim3(256), 0, stream>>>(part, bias, out);
}

// Round 12
// 25.394 us; speedup vs baseline: 3.5224x; 1.1056x over previous
//
#include <hip/hip_runtime.h>
#include <hip/hip_bf16.h>

// B=16, Ci=16, Co=16, H=W=24, hidden=64.
// kt:    K[dy47][dxi][o][i] bf16; dy47 = dy+23 in [0,47), dxi = dx+24 in [0,49).
//        dxi stride in shorts = 256. (Round 9-11 bug: used 512/ww -> OOB fault.)
// vpad2: bf16 [y'=40][x'=40][b=16][i=16], y'=h+8, x'=w+8, zero halo.
// conv_part: grid (wt6, hg6, oct7), 512 thr = 8 waves = (tq 0..3) x (hhh 0..1).
//   Wave tile: 16o x 16b x (2h x 4w) = 8 accumulators; one dy per wave.
//   Sliding A reuse: A(ww,dxp+1) = A(ww-2,dxp) -> 2 fresh A + 2 B per 8 MFMAs.
//   Two-phase 32KB LDS reduce over tq (one phase per hh) -> 7 octet partials.

typedef __attribute__((ext_vector_type(8))) short bf16x8;
typedef __attribute__((ext_vector_type(4))) float f32x4;

#define KT_ELEMS (47*49*256)          // 589,568 bf16
#define VPAD2_ELEMS (40*40*256)       // 409,600 bf16
#define NROWS (47*49)                 // 2303 MLP rows
#define NPOS 576                      // 24*24 output positions
#define NOCT 7                        // dy octets (7*4 = 28 >= 27)
#define PREP_BUILD_BLOCKS 288         // ceil(2303/8)
#define PREP_PAD_BLOCKS (VPAD2_ELEMS/256)   // 1600

// ---------------- Kernel 1: prep = build K table + pad v (fused grid) -------
__launch_bounds__(256)
__global__ void prep(const float* __restrict__ v,
                     const float* __restrict__ w1, const float* __restrict__ b1,
                     const float* __restrict__ w2, const float* __restrict__ b2,
                     __hip_bfloat16* __restrict__ kt, __hip_bfloat16* __restrict__ vpad)
{
    const int tid = threadIdx.x;

    if (blockIdx.x >= PREP_BUILD_BLOCKS) {
        // ---- pad part: vpad2[y][x][b][i] ----
        int idx = (blockIdx.x - PREP_BUILD_BLOCKS)*256 + tid;
        if (idx >= VPAD2_ELEMS) return;
        int i = idx & 15;
        int b = (idx >> 4) & 15;
        int s = idx >> 8;             // y*40 + x
        int x = s % 40;
        int y = s / 40;
        int h = y - 8, w = x - 8;
        float val = 0.0f;
        if (h >= 0 && h < 24 && w >= 0 && w < 24)
            val = v[((b*16 + i)*24 + h)*24 + w];
        vpad[idx] = __float2bfloat16(val);
        return;
    }

    // ---- build part: 8 rows of the [2303 x 256] K GEMM per block ----
    __shared__ float ty_s[47];
    __shared__ float tx_s[49];
    __shared__ float hid_s[8][64];
    const int r0 = blockIdx.x * 8;

    if (tid < 47)               ty_s[tid]      = tanhf((float)(tid - 23) * (1.0f/6.0f));
    if (tid >= 64 && tid < 113) tx_s[tid - 64] = tanhf((float)(tid - 64 - 24) * (1.0f/6.0f));
    __syncthreads();

    #pragma unroll
    for (int k = 0; k < 2; ++k) {
        int idx = k*256 + tid;
        int rr  = idx >> 6;
        int j   = idx & 63;
        int r   = r0 + rr;
        if (r >= NROWS) r = NROWS - 1;
        int dy47 = r / 49;
        int dxi  = r % 49;
        float x = ty_s[dy47]*w1[2*j] + tx_s[dxi]*w1[2*j+1] + b1[j];
        hid_s[rr][j] = 0.5f*x*(1.0f + erff(x*0.70710678118f));
    }
    __syncthreads();

    const int c = tid;
    float acc[8];
    const float bb = b2[c];
    #pragma unroll
    for (int r = 0; r < 8; ++r) acc[r] = bb;

    const float4* w2v = (const float4*)w2;
    #pragma unroll
    for (int jv = 0; jv < 16; ++jv) {
        float4 wv = w2v[c*16 + jv];
        #pragma unroll
        for (int e = 0; e < 4; ++e) {
            float we = ((const float*)&wv)[e];
            int j = jv*4 + e;
            #pragma unroll
            for (int r = 0; r < 8; ++r)
                acc[r] += hid_s[r][j] * we;
        }
    }

    #pragma unroll
    for (int rr = 0; rr < 8; ++rr) {
        int r = r0 + rr;
        if (r >= NROWS) break;
        kt[r*256 + c] = __float2bfloat16(acc[rr]);
    }
}

// ---------------- Kernel 2: main MFMA correlation (octet partials) ----------
// 8 waves: wv = tq + 4*hhh. Wave: one dy (t = oct*4+tq), rows h0+hhh*2+{0,1},
// cols w0..w0+3, 12 dxp steps. A slides (2 fresh/step), B 2 fresh/step.
// A(ww,dxp): dxi = 24 - w0 - ww + 2*dxp + d; dxi step = 256 shorts.
// dxi range check: min = 24-20-3+0+0 = 1, max(refill) = 24-0+22+1 = 47 < 49. OK.
__launch_bounds__(512)
__global__ void conv_part(const __hip_bfloat16* __restrict__ kt_,
                          const __hip_bfloat16* __restrict__ vpad_,
                          float* __restrict__ part)
{
    __shared__ f32x4 red[8][4][64];   // [src wave][ww][lane], 32 KB
    const short* kt = (const short*)kt_;
    const short* vp = (const short*)vpad_;

    const int wt  = blockIdx.x;       // 0..5  -> w0 = wt*4
    const int hg  = blockIdx.y;       // 0..5  -> h0 = hg*4
    const int oct = blockIdx.z;       // 0..6
    const int w0  = wt * 4;
    const int h0  = hg * 4;

    const int tid  = threadIdx.x;
    const int lane = tid & 63;
    const int wv   = tid >> 6;        // 0..7
    const int tq   = wv & 3;
    const int hhh  = wv >> 2;         // h-pair of this wave
    const int n    = lane & 15;       // A: o row; B: b col
    const int g    = lane >> 4;       // k-group
    const int d    = g >> 1;          // dx sub-offset within pair
    const int ih   = (g & 1) * 8;     // i-half

    const int t = oct*4 + tq;         // dy index; dy = t - h0 - 3, valid t<27

    f32x4 acc[2][4];
    #pragma unroll
    for (int hh = 0; hh < 2; ++hh)
        #pragma unroll
        for (int ww = 0; ww < 4; ++ww) acc[hh][ww] = (f32x4){0.f,0.f,0.f,0.f};

    if (t < 27) {
        const int dy47 = t - h0 + 20;                       // in [0,46]
        // base: dxi(ww=0,dxp=0) = 24 - w0 + d
        const short* apb = kt + ((long)(dy47*49 + (24 - w0 + d)))*256 + n*16 + ih;
        // B(hh,dxp): vp[(y'*40 + x')*256 + b*16 + ih], y' = t+hhh*2+hh+5, x' = 8+2dxp+d
        const short* bpb = vp + ((long)((t + hhh*2 + 5)*40 + (8 + d)))*256 + n*16 + ih;

        bf16x8 av[4];
        av[0] = *(const bf16x8*)(apb);            // ww=0: dxi base
        av[1] = *(const bf16x8*)(apb - 256);      // ww=1: dxi-1
        av[2] = *(const bf16x8*)(apb - 512);      // ww=2: dxi-2
        av[3] = *(const bf16x8*)(apb - 768);      // ww=3: dxi-3

        #pragma unroll
        for (int dxp = 0; dxp < 12; ++dxp) {
            bf16x8 bv0 = *(const bf16x8*)(bpb +         dxp*512);   // x' += 2/dxp
            bf16x8 bv1 = *(const bf16x8*)(bpb + 10240 + dxp*512);   // +1 y' row
            #pragma unroll
            for (int ww = 0; ww < 4; ++ww) {
                acc[0][ww] = __builtin_amdgcn_mfma_f32_16x16x32_bf16(av[ww], bv0, acc[0][ww], 0, 0, 0);
                acc[1][ww] = __builtin_amdgcn_mfma_f32_16x16x32_bf16(av[ww], bv1, acc[1][ww], 0, 0, 0);
            }
            if (dxp < 11) {
                av[2] = av[0];                    // A(2,dxp+1) = A(0,dxp)
                av[3] = av[1];                    // A(3,dxp+1) = A(1,dxp)
                av[0] = *(const bf16x8*)(apb + (2*dxp + 2)*256);    // dxi(0,dxp+1)
                av[1] = *(const bf16x8*)(apb + (2*dxp + 1)*256);    // dxi(1,dxp+1)
            }
        }
    }

    // Two-phase reduce (32 KB): phase hh stores acc[hh][*], then wave wv
    // writes output (hhh2 = wv>>2, ww2 = wv&3) for row h = h0 + hhh2*2 + hh.
    #pragma unroll
    for (int hh = 0; hh < 2; ++hh) {
        if (hh) __syncthreads();                  // protect red reuse
        #pragma unroll
        for (int ww = 0; ww < 4; ++ww) red[wv][ww][lane] = acc[hh][ww];
        __syncthreads();

        const int hhh2 = wv >> 2;
        const int ww2  = wv & 3;
        f32x4 s = red[0 + 0][ww2][lane];
        s = red[4*hhh2 + 0][ww2][lane];
        s += red[4*hhh2 + 1][ww2][lane];
        s += red[4*hhh2 + 2][ww2][lane];
        s += red[4*hhh2 + 3][ww2][lane];

        const int h = h0 + hhh2*2 + hh;
        const int w = w0 + ww2;
        const int p = h*24 + w;
        // part layout: [oct][p][b*16 + o], o = g*4+e contiguous -> f32x4
        float* dst = part + ((size_t)oct*NPOS + p)*256 + (n*16 + g*4);
        *(f32x4*)dst = s;
    }
}

// ---------------- Kernel 3: combine octets + scale + bias (transpose) -------
__launch_bounds__(256)
__global__ void combine(const float* __restrict__ part, const float* __restrict__ bias,
                        float* __restrict__ out)
{
    __shared__ float lds[16][257];
    const int tid = threadIdx.x;
    const int p0  = blockIdx.x * 16;

    #pragma unroll
    for (int pp = 0; pp < 16; ++pp) {
        float s = 0.f;
        #pragma unroll
        for (int oct = 0; oct < NOCT; ++oct)
            s += part[((size_t)oct*NPOS + p0 + pp)*256 + tid];
        lds[pp][tid] = s;
    }
    __syncthreads();

    const int pp = tid & 15;
    const int g  = tid >> 4;          // 0..15 across the block
    const float sc = 1.0f/576.0f;
    #pragma unroll
    for (int cc = 0; cc < 16; ++cc) {
        int c2 = cc*16 + g;           // c2 = b*16 + o
        out[(size_t)c2*576 + p0 + pp] = lds[pp][c2]*sc + bias[c2 & 15];
    }
}

extern "C" void kernel_launch(void* const* d_in, const int* in_sizes, int n_in,
                              void* d_out, int out_size, void* d_ws, size_t ws_size,
                              hipStream_t stream)
{
    const float* v    = (const float*)d_in[0];
    const float* w1   = (const float*)d_in[1];
    const float* b1   = (const float*)d_in[2];
    const float* w2   = (const float*)d_in[3];
    const float* b2   = (const float*)d_in[4];
    const float* bias = (const float*)d_in[5];
    float* out = (float*)d_out;

    char* ws = (char*)d_ws;
    __hip_bfloat16* kt   = (__hip_bfloat16*)ws;                          // 1,179,136 B
    __hip_bfloat16* vpad = (__hip_bfloat16*)(ws + (size_t)KT_ELEMS*2);   //   819,200 B
    float* part = (float*)(ws + (size_t)KT_ELEMS*2 + (size_t)VPAD2_ELEMS*2); // 4,128,768 B

    prep<<<dim3(PREP_BUILD_BLOCKS + PREP_PAD_BLOCKS), dim3(256), 0, stream>>>(
        v, w1, b1, w2, b2, kt, vpad);
    conv_part<<<dim3(6, 6, NOCT), dim3(512), 0, stream>>>(kt, vpad, part);
    combine<<<dim3(NPOS/16), dim3(256), 0, stream>>>(part, bias, out);
}